// Round 7
// baseline (126.136 us; speedup 1.0000x reference)
//
#include <hip/hip_runtime.h>

typedef __attribute__((ext_vector_type(8))) short bf16x8;
typedef __attribute__((ext_vector_type(4))) float f32x4;

#define Bq 256
#define Nq 128
#define Cq 256
#define TP 16            // particles per block tile (GEMM M)
#define NBLK (Nq / TP)   // 8 tiles per batch

__device__ __forceinline__ unsigned short f2bf(float f) {
    unsigned int u = __float_as_uint(f);
    u += 0x7fffu + ((u >> 16) & 1u);   // RNE
    return (unsigned short)(u >> 16);
}

struct ushort4_t { unsigned short x, y, z, w; };

__device__ __forceinline__ void fma4(float4& a, const float4& k, const float4& x) {
    a.x = fmaf(k.x, x.x, a.x);
    a.y = fmaf(k.y, x.y, a.y);
    a.z = fmaf(k.z, x.z, a.z);
    a.w = fmaf(k.w, x.w, a.w);
}

// -------- kernel 0: pack dense_w fp32 -> bf16 in MFMA B-fragment order ------
// wp[((kt*16 + nt)*64 + lane)*8 + j] = W[k = kt*32 + (lane>>4)*8 + j][n = nt*16 + (lane&15)]
__global__ __launch_bounds__(256) void wpack_kernel(const float* __restrict__ dw,
                                                    unsigned short* __restrict__ wp) {
    int tid = blockIdx.x * 256 + threadIdx.x;
    int j    = tid & 7;
    int lane = (tid >> 3) & 63;
    int nt   = (tid >> 9) & 15;
    int kt   = tid >> 13;
    int k = kt * 32 + (lane >> 4) * 8 + j;
    int n = nt * 16 + (lane & 15);
    wp[tid] = f2bf(dw[k * Cq + n]);
}

// -------- kernel A: idx + match scan + conv -> bf16 A-fragments (global) ----
// Barrier-free: minima & grid indices live in registers (per-wave redundant
// reduction), scan exchanges packed (ge<<8|gp) via ds_bpermute, and each
// particle's list is written and read by the same wave.
__global__ __launch_bounds__(256, 4) void conv_kernel(
    const float* __restrict__ x, const float* __restrict__ eta, const float* __restrict__ phi,
    const float* __restrict__ ck, const float* __restrict__ cb,
    unsigned short* __restrict__ afr) {
    const int blk = blockIdx.x;
    const int b  = blk >> 3;
    const int p0 = (blk & (NBLK - 1)) * TP;
    const int t  = threadIdx.x;
    const int lane = t & 63, wave = t >> 6;

    __shared__ int s_cnt[TP];
    __shared__ unsigned short s_list[TP][132];   // m | (k<<7)

    const int pp = t >> 4, cg = t & 15;          // pp == 4*wave + (lane>>4)

    // ---- per-wave minima over all 128 particles (registers only) ----
    float e0 = eta[b * Nq + lane], e1 = eta[b * Nq + 64 + lane];
    float q0 = phi[b * Nq + lane], q1 = phi[b * Nq + 64 + lane];
    float emin = fminf(e0, e1), pmin = fminf(q0, q1);
#pragma unroll
    for (int off = 32; off > 0; off >>= 1) {
        emin = fminf(emin, __shfl_xor(emin, off));
        pmin = fminf(pmin, __shfl_xor(pmin, off));
    }
    // packed grid indices, bit-matching numpy fp32 path (values < 40)
    int pk0 = ((int)((e0 - emin) / 0.05f) << 8) | (int)((q0 - pmin) / 0.05f);
    int pk1 = ((int)((e1 - emin) / 0.05f) << 8) | (int)((q1 - pmin) / 0.05f);

    if ((lane >> 4) == 0) s_cnt[4 * wave + (lane & 3)] = 0;   // own 4 counters
    __threadfence_block();

    // ---- match scan: thread (pp,cg) scans m = cg*8 .. cg*8+7 ----
    {
        int P = p0 + pp;
        int pa = (P & 63) << 2;
        int t0 = __builtin_amdgcn_ds_bpermute(pa, pk0);
        int t1 = __builtin_amdgcn_ds_bpermute(pa, pk1);
        int tp = (P < 64) ? t0 : t1;
        int th = tp >> 8, tw = tp & 255;
#pragma unroll
        for (int i = 0; i < 8; ++i) {
            int m = cg * 8 + i;
            int ma = (m & 63) << 2;
            int c0 = __builtin_amdgcn_ds_bpermute(ma, pk0);
            int c1 = __builtin_amdgcn_ds_bpermute(ma, pk1);
            int cp = (cg < 8) ? c0 : c1;          // m<64 iff cg<8
            int dh = (cp >> 8) - th, dv = (cp & 255) - tw;
            if (dh >= -1 && dh <= 1 && dv >= -1 && dv <= 1) {
                int k = (dh + 1) * 3 + (dv + 1);  // cross-correlation tap
                int pos = atomicAdd(&s_cnt[pp], 1);
                s_list[pp][pos] = (unsigned short)(m | (k << 7));
            }
        }
    }
    __threadfence_block();   // same-wave producer/consumer: no barrier needed

    // ---- conv: thread = (pp, cg); channels c = j*64 + cg*4 + i ----
    const float4* x4  = (const float4*)x + (size_t)b * (Nq * Cq / 4) + cg;
    const float4* ck4 = (const float4*)ck + cg;     // 9 KB, L2/L3-hot
    const float4* cb4 = (const float4*)cb + cg;
    float4 a0 = cb4[0], a1 = cb4[16], a2 = cb4[32], a3 = cb4[48];

    const int cnt = s_cnt[pp];
    const unsigned short* lst = s_list[pp];
    int i = 0;
    for (; i + 2 <= cnt; i += 2) {
        int e0_ = lst[i], e1_ = lst[i + 1];
        const float4* xp0 = x4  + ((e0_ & 127) << 6);
        const float4* kp0 = ck4 + ((e0_ >> 7)  << 6);
        const float4* xp1 = x4  + ((e1_ & 127) << 6);
        const float4* kp1 = ck4 + ((e1_ >> 7)  << 6);
        float4 X00 = xp0[0], X01 = xp0[16], X02 = xp0[32], X03 = xp0[48];
        float4 X10 = xp1[0], X11 = xp1[16], X12 = xp1[32], X13 = xp1[48];
        float4 K00 = kp0[0], K01 = kp0[16], K02 = kp0[32], K03 = kp0[48];
        float4 K10 = kp1[0], K11 = kp1[16], K12 = kp1[32], K13 = kp1[48];
        fma4(a0, K00, X00); fma4(a1, K01, X01);
        fma4(a2, K02, X02); fma4(a3, K03, X03);
        fma4(a0, K10, X10); fma4(a1, K11, X11);
        fma4(a2, K12, X12); fma4(a3, K13, X13);
    }
    if (i < cnt) {
        int e0_ = lst[i];
        const float4* xp0 = x4  + ((e0_ & 127) << 6);
        const float4* kp0 = ck4 + ((e0_ >> 7)  << 6);
        float4 X00 = xp0[0], X01 = xp0[16], X02 = xp0[32], X03 = xp0[48];
        float4 K00 = kp0[0], K01 = kp0[16], K02 = kp0[32], K03 = kp0[48];
        fma4(a0, K00, X00); fma4(a1, K01, X01);
        fma4(a2, K02, X02); fma4(a3, K03, X03);
    }

    // write swizzled bf16 A-fragments to global (same mapping GEMM reads)
    unsigned short* ab = afr + (size_t)blk * 4096;
    const int g = (cg >> 1) & 3;
    const int lidx = ((pp + 2 * g) & 15) | (g << 4);
    const int off = (cg & 1) * 4;
    float4 aj[4] = {a0, a1, a2, a3};
#pragma unroll
    for (int j = 0; j < 4; ++j) {
        int kt = j * 2 + (cg >> 3);
        ushort4_t v;
        v.x = f2bf(aj[j].x); v.y = f2bf(aj[j].y);
        v.z = f2bf(aj[j].z); v.w = f2bf(aj[j].w);
        *(ushort4_t*)&ab[(kt * 64 + lidx) * 8 + off] = v;
    }
}

// -------- kernel B: MFMA dense + LN + residual ----
__global__ __launch_bounds__(256, 4) void gemm_kernel(
    const float* __restrict__ x, const unsigned short* __restrict__ afr,
    const unsigned short* __restrict__ wp, const float* __restrict__ db,
    const float* __restrict__ gamma, const float* __restrict__ beta,
    float* __restrict__ out) {
    const int blk = blockIdx.x;
    const int b  = blk >> 3;
    const int p0 = (blk & (NBLK - 1)) * TP;
    const int lane = threadIdx.x & 63, wave = threadIdx.x >> 6;

    __shared__ float s_sum[TP][4], s_sq[TP][4];

    const int g2 = lane >> 4, m2 = lane & 15;
    const int alidx = ((m2 + 2 * g2) & 15) | (g2 << 4);
    const unsigned short* ab = afr + (size_t)blk * 4096;

    // residual x prefetch (overlaps GEMM; x is L3-resident)
    float xr[4][4];
    const int gbase0 = (b * Nq + p0 + g2 * 4) * Cq + wave * 64 + m2;
#pragma unroll
    for (int r = 0; r < 4; ++r)
#pragma unroll
        for (int ntl = 0; ntl < 4; ++ntl)
            xr[r][ntl] = x[gbase0 + r * Cq + ntl * 16];

    f32x4 acc[4];
#pragma unroll
    for (int ntl = 0; ntl < 4; ++ntl) acc[ntl] = (f32x4){0.f, 0.f, 0.f, 0.f};

#pragma unroll
    for (int kt2 = 0; kt2 < 8; ++kt2) {
        bf16x8 af = *reinterpret_cast<const bf16x8*>(&ab[(kt2 * 64 + alidx) * 8]);
#pragma unroll
        for (int ntl = 0; ntl < 4; ++ntl) {
            int nt = wave * 4 + ntl;
            bf16x8 bfr = *reinterpret_cast<const bf16x8*>(&wp[((kt2 * 16 + nt) * 64 + lane) * 8]);
            acc[ntl] = __builtin_amdgcn_mfma_f32_16x16x32_bf16(af, bfr, acc[ntl], 0, 0, 0);
        }
    }

    // ---- epilogue: +db, LN stats per row (row = g2*4 + r), residual ----
    float dbv[4], gv[4], bv[4];
#pragma unroll
    for (int ntl = 0; ntl < 4; ++ntl) {
        int col = (wave * 4 + ntl) * 16 + m2;
        dbv[ntl] = db[col]; gv[ntl] = gamma[col]; bv[ntl] = beta[col];
    }
#pragma unroll
    for (int r = 0; r < 4; ++r) {
        float a = 0.f, q = 0.f;
#pragma unroll
        for (int ntl = 0; ntl < 4; ++ntl) {
            float y = acc[ntl][r] + dbv[ntl];
            a += y; q += y * y;
        }
#pragma unroll
        for (int off = 8; off >= 1; off >>= 1) {
            a += __shfl_xor(a, off);
            q += __shfl_xor(q, off);
        }
        if (m2 == 0) {
            int row = g2 * 4 + r;
            s_sum[row][wave] = a;
            s_sq[row][wave]  = q;
        }
    }
    __syncthreads();

#pragma unroll
    for (int r = 0; r < 4; ++r) {
        int row = g2 * 4 + r;
        float s = s_sum[row][0] + s_sum[row][1] + s_sum[row][2] + s_sum[row][3];
        float q = s_sq[row][0] + s_sq[row][1] + s_sq[row][2] + s_sq[row][3];
        float mean = s * (1.0f / Cq);
        float var  = q * (1.0f / Cq) - mean * mean;
        float inv  = rsqrtf(var + 1e-6f);
        int gbase = (b * Nq + p0 + row) * Cq + wave * 64 + m2;
#pragma unroll
        for (int ntl = 0; ntl < 4; ++ntl) {
            float y = acc[ntl][r] + dbv[ntl];
            out[gbase + ntl * 16] = xr[r][ntl] + (y - mean) * inv * gv[ntl] + bv[ntl];
        }
    }
}

extern "C" void kernel_launch(void* const* d_in, const int* in_sizes, int n_in,
                              void* d_out, int out_size, void* d_ws, size_t ws_size,
                              hipStream_t stream) {
    const float* x     = (const float*)d_in[0];
    const float* eta   = (const float*)d_in[1];
    const float* phi   = (const float*)d_in[2];
    const float* ck    = (const float*)d_in[3];
    const float* cb    = (const float*)d_in[4];
    const float* dw    = (const float*)d_in[5];
    const float* db    = (const float*)d_in[6];
    const float* gamma = (const float*)d_in[7];
    const float* beta  = (const float*)d_in[8];
    float* out = (float*)d_out;

    unsigned short* wpk = (unsigned short*)d_ws;          // 65536 bf16 = 128 KB
    unsigned short* afr = wpk + 65536;                    // 2048 * 4096 bf16 = 16 MB

    wpack_kernel<<<Cq, 256, 0, stream>>>(dw, wpk);
    conv_kernel<<<Bq * NBLK, 256, 0, stream>>>(x, eta, phi, ck, cb, afr);
    gemm_kernel<<<Bq * NBLK, 256, 0, stream>>>(x, afr, wpk, db, gamma, beta, out);
}

// Round 8
// 116.392 us; speedup vs baseline: 1.0837x; 1.0837x over previous
//
#include <hip/hip_runtime.h>

typedef __attribute__((ext_vector_type(8))) short bf16x8;
typedef __attribute__((ext_vector_type(4))) float f32x4;

#define Bq 256
#define Nq 128
#define Cq 256
#define TP 32            // particles per block (GEMM M)
#define NBLK (Nq / TP)   // 4 blocks per batch

__device__ __forceinline__ unsigned short f2bf(float f) {
    unsigned int u = __float_as_uint(f);
    u += 0x7fffu + ((u >> 16) & 1u);   // RNE
    return (unsigned short)(u >> 16);
}

struct ushort4_t { unsigned short x, y, z, w; };

__device__ __forceinline__ void fma4(float4& a, const float4& k, const float4& x) {
    a.x = fmaf(k.x, x.x, a.x);
    a.y = fmaf(k.y, x.y, a.y);
    a.z = fmaf(k.z, x.z, a.z);
    a.w = fmaf(k.w, x.w, a.w);
}

// -------- kernel 0: pack dense_w fp32 -> bf16 in MFMA B-fragment order ------
// wp[((kt*16 + nt)*64 + lane)*8 + j] = W[k = kt*32 + (lane>>4)*8 + j][n = nt*16 + (lane&15)]
__global__ __launch_bounds__(256) void wpack_kernel(const float* __restrict__ dw,
                                                    unsigned short* __restrict__ wp) {
    int tid = blockIdx.x * 256 + threadIdx.x;
    int j    = tid & 7;
    int lane = (tid >> 3) & 63;
    int nt   = (tid >> 9) & 15;
    int kt   = tid >> 13;
    int k = kt * 32 + (lane >> 4) * 8 + j;
    int n = nt * 16 + (lane & 15);
    wp[tid] = f2bf(dw[k * Cq + n]);
}

// -------- fused: idx + conv-at-particles + MFMA dense (M=32) + LN + residual
__global__ __launch_bounds__(256, 4) void fused_kernel(
    const float* __restrict__ x, const float* __restrict__ eta, const float* __restrict__ phi,
    const float* __restrict__ ck, const float* __restrict__ cb,
    const unsigned short* __restrict__ wp, const float* __restrict__ db,
    const float* __restrict__ gamma, const float* __restrict__ beta,
    float* __restrict__ out) {
    const int b  = blockIdx.x >> 2;
    const int p0 = (blockIdx.x & (NBLK - 1)) * TP;
    const int t  = threadIdx.x;
    const int lane = t & 63, wave = t >> 6;

    __shared__ float s_ck[9 * Cq];                   // 9 KB
    __shared__ int   s_cnt[TP];
    __shared__ unsigned short s_list[TP][130];       // m | (k<<7), 8.1 KB
    __shared__ unsigned short s_A[2 * 8 * 64 * 8] __attribute__((aligned(16)));  // 16 KB
    __shared__ float s_sum[TP][4], s_sq[TP][4];      // 1 KB

    const int pp = t >> 4, cg = t & 15;   // group pp handles particles pp, pp+16

    // ---- per-wave minima over all 128 particles (registers only) ----
    float e0 = eta[b * Nq + lane], e1 = eta[b * Nq + 64 + lane];
    float q0 = phi[b * Nq + lane], q1 = phi[b * Nq + 64 + lane];
    float emin = fminf(e0, e1), pmin = fminf(q0, q1);
#pragma unroll
    for (int off = 32; off > 0; off >>= 1) {
        emin = fminf(emin, __shfl_xor(emin, off));
        pmin = fminf(pmin, __shfl_xor(pmin, off));
    }
    // packed grid indices, bit-matching numpy fp32 path (values < 40)
    int pk0 = ((int)((e0 - emin) / 0.05f) << 8) | (int)((q0 - pmin) / 0.05f);
    int pk1 = ((int)((e1 - emin) / 0.05f) << 8) | (int)((q1 - pmin) / 0.05f);

    // ---- stage conv kernel to LDS + init counters ----
    for (int i = t; i < 9 * Cq; i += 256) s_ck[i] = ck[i];
    if (t < TP) s_cnt[t] = 0;
    __syncthreads();

    // ---- match scan: thread (pp,cg) scans m = cg*8..cg*8+7 for BOTH targets
    {
        int PA = p0 + pp, PB = PA + 16;
        int a0_ = __builtin_amdgcn_ds_bpermute((PA & 63) << 2, pk0);
        int a1_ = __builtin_amdgcn_ds_bpermute((PA & 63) << 2, pk1);
        int b0_ = __builtin_amdgcn_ds_bpermute((PB & 63) << 2, pk0);
        int b1_ = __builtin_amdgcn_ds_bpermute((PB & 63) << 2, pk1);
        int tpA = (PA < 64) ? a0_ : a1_;
        int tpB = (PB < 64) ? b0_ : b1_;
        int thA = tpA >> 8, twA = tpA & 255;
        int thB = tpB >> 8, twB = tpB & 255;
#pragma unroll
        for (int i = 0; i < 8; ++i) {
            int m = cg * 8 + i;
            int ma = (m & 63) << 2;
            int c0 = __builtin_amdgcn_ds_bpermute(ma, pk0);
            int c1 = __builtin_amdgcn_ds_bpermute(ma, pk1);
            int cp = (cg < 8) ? c0 : c1;          // m<64 iff cg<8
            int mh = cp >> 8, mw = cp & 255;
            int dhA = mh - thA, dvA = mw - twA;
            if (dhA >= -1 && dhA <= 1 && dvA >= -1 && dvA <= 1) {
                int k = (dhA + 1) * 3 + (dvA + 1);
                int pos = atomicAdd(&s_cnt[pp], 1);
                s_list[pp][pos] = (unsigned short)(m | (k << 7));
            }
            int dhB = mh - thB, dvB = mw - twB;
            if (dhB >= -1 && dhB <= 1 && dvB >= -1 && dvB <= 1) {
                int k = (dhB + 1) * 3 + (dvB + 1);
                int pos = atomicAdd(&s_cnt[pp + 16], 1);
                s_list[pp + 16][pos] = (unsigned short)(m | (k << 7));
            }
        }
    }
    __threadfence_block();   // scan writers == conv readers (same wave)

    // ---- conv for the two particles; channels c = j*64 + cg*4 + i ----
    {
        const float4* x4  = (const float4*)x + (size_t)b * (Nq * Cq / 4) + cg;
        const float4* ck4 = (const float4*)s_ck + cg;
        const float4* cb4 = (const float4*)cb + cg;
        const int g = (cg >> 1) & 3;
        const int off = (cg & 1) * 4;

#pragma unroll
        for (int half = 0; half < 2; ++half) {
            const int lp = pp + half * 16;        // local particle index
            float4 a0 = cb4[0], a1 = cb4[16], a2 = cb4[32], a3 = cb4[48];
            const int cnt = s_cnt[lp];
            const unsigned short* lst = s_list[lp];
            int i = 0;
            for (; i + 2 <= cnt; i += 2) {
                int e0_ = lst[i], e1_ = lst[i + 1];
                const float4* xp0 = x4  + ((e0_ & 127) << 6);
                const float4* kp0 = ck4 + ((e0_ >> 7)  << 6);
                const float4* xp1 = x4  + ((e1_ & 127) << 6);
                const float4* kp1 = ck4 + ((e1_ >> 7)  << 6);
                float4 X00 = xp0[0], X01 = xp0[16], X02 = xp0[32], X03 = xp0[48];
                float4 X10 = xp1[0], X11 = xp1[16], X12 = xp1[32], X13 = xp1[48];
                float4 K00 = kp0[0], K01 = kp0[16], K02 = kp0[32], K03 = kp0[48];
                float4 K10 = kp1[0], K11 = kp1[16], K12 = kp1[32], K13 = kp1[48];
                fma4(a0, K00, X00); fma4(a1, K01, X01);
                fma4(a2, K02, X02); fma4(a3, K03, X03);
                fma4(a0, K10, X10); fma4(a1, K11, X11);
                fma4(a2, K12, X12); fma4(a3, K13, X13);
            }
            if (i < cnt) {
                int e0_ = lst[i];
                const float4* xp0 = x4  + ((e0_ & 127) << 6);
                const float4* kp0 = ck4 + ((e0_ >> 7)  << 6);
                float4 X00 = xp0[0], X01 = xp0[16], X02 = xp0[32], X03 = xp0[48];
                float4 K00 = kp0[0], K01 = kp0[16], K02 = kp0[32], K03 = kp0[48];
                fma4(a0, K00, X00); fma4(a1, K01, X01);
                fma4(a2, K02, X02); fma4(a3, K03, X03);
            }

            // write swizzled bf16 A-fragments (mt = half)
            const int pl = pp;                    // index within 16-row group
            const int lidx = ((pl + 2 * g) & 15) | (g << 4);
            float4 aj[4] = {a0, a1, a2, a3};
#pragma unroll
            for (int j = 0; j < 4; ++j) {
                int kt = j * 2 + (cg >> 3);
                ushort4_t v;
                v.x = f2bf(aj[j].x); v.y = f2bf(aj[j].y);
                v.z = f2bf(aj[j].z); v.w = f2bf(aj[j].w);
                *(ushort4_t*)&s_A[((half * 8 + kt) * 64 + lidx) * 8 + off] = v;
            }
        }
    }
    __syncthreads();   // cross-wave: GEMM reads all 32 rows

    // ---- GEMM: 2 mtiles x 4 ntl per wave, K = 8 steps of 32 ----
    f32x4 acc[2][4];
#pragma unroll
    for (int mt = 0; mt < 2; ++mt)
#pragma unroll
        for (int ntl = 0; ntl < 4; ++ntl) acc[mt][ntl] = (f32x4){0.f, 0.f, 0.f, 0.f};

    const int g2 = lane >> 4, m2 = lane & 15;
    const int alidx = ((m2 + 2 * g2) & 15) | (g2 << 4);
#pragma unroll
    for (int kt2 = 0; kt2 < 8; ++kt2) {
        bf16x8 af0 = *reinterpret_cast<const bf16x8*>(&s_A[((0 * 8 + kt2) * 64 + alidx) * 8]);
        bf16x8 af1 = *reinterpret_cast<const bf16x8*>(&s_A[((1 * 8 + kt2) * 64 + alidx) * 8]);
#pragma unroll
        for (int ntl = 0; ntl < 4; ++ntl) {
            int nt = wave * 4 + ntl;
            bf16x8 bfr = *reinterpret_cast<const bf16x8*>(&wp[((kt2 * 16 + nt) * 64 + lane) * 8]);
            acc[0][ntl] = __builtin_amdgcn_mfma_f32_16x16x32_bf16(af0, bfr, acc[0][ntl], 0, 0, 0);
            acc[1][ntl] = __builtin_amdgcn_mfma_f32_16x16x32_bf16(af1, bfr, acc[1][ntl], 0, 0, 0);
        }
    }

    // ---- epilogue: +db, LN stats per row (row = mt*16 + g2*4 + r) ----
    float dbv[4], gv[4], bv[4];
#pragma unroll
    for (int ntl = 0; ntl < 4; ++ntl) {
        int col = (wave * 4 + ntl) * 16 + m2;
        dbv[ntl] = db[col]; gv[ntl] = gamma[col]; bv[ntl] = beta[col];
    }
#pragma unroll
    for (int mt = 0; mt < 2; ++mt)
#pragma unroll
    for (int r = 0; r < 4; ++r) {
        float a = 0.f, q = 0.f;
#pragma unroll
        for (int ntl = 0; ntl < 4; ++ntl) {
            float y = acc[mt][ntl][r] + dbv[ntl];
            a += y; q += y * y;
        }
#pragma unroll
        for (int off = 8; off >= 1; off >>= 1) {
            a += __shfl_xor(a, off);
            q += __shfl_xor(q, off);
        }
        if (m2 == 0) {
            int row = mt * 16 + g2 * 4 + r;
            s_sum[row][wave] = a;
            s_sq[row][wave]  = q;
        }
    }
    __syncthreads();   // cross-wave: LN sums span all 4 waves' column groups

#pragma unroll
    for (int mt = 0; mt < 2; ++mt)
#pragma unroll
    for (int r = 0; r < 4; ++r) {
        int row = mt * 16 + g2 * 4 + r;
        float s = s_sum[row][0] + s_sum[row][1] + s_sum[row][2] + s_sum[row][3];
        float q = s_sq[row][0] + s_sq[row][1] + s_sq[row][2] + s_sq[row][3];
        float mean = s * (1.0f / Cq);
        float var  = q * (1.0f / Cq) - mean * mean;
        float inv  = rsqrtf(var + 1e-6f);
        int gbase = (b * Nq + p0 + row) * Cq + wave * 64 + m2;
#pragma unroll
        for (int ntl = 0; ntl < 4; ++ntl) {
            float y = acc[mt][ntl][r] + dbv[ntl];
            int idx = gbase + ntl * 16;
            out[idx] = x[idx] + (y - mean) * inv * gv[ntl] + bv[ntl];
        }
    }
}

extern "C" void kernel_launch(void* const* d_in, const int* in_sizes, int n_in,
                              void* d_out, int out_size, void* d_ws, size_t ws_size,
                              hipStream_t stream) {
    const float* x     = (const float*)d_in[0];
    const float* eta   = (const float*)d_in[1];
    const float* phi   = (const float*)d_in[2];
    const float* ck    = (const float*)d_in[3];
    const float* cb    = (const float*)d_in[4];
    const float* dw    = (const float*)d_in[5];
    const float* db    = (const float*)d_in[6];
    const float* gamma = (const float*)d_in[7];
    const float* beta  = (const float*)d_in[8];
    float* out = (float*)d_out;

    unsigned short* wpk = (unsigned short*)d_ws;   // 65536 bf16 = 128 KB

    wpack_kernel<<<Cq, 256, 0, stream>>>(dw, wpk);
    fused_kernel<<<Bq * NBLK, 256, 0, stream>>>(x, eta, phi, ck, cb, wpk, db,
                                                gamma, beta, out);
}